// Round 1
// baseline (1608.668 us; speedup 1.0000x reference)
//
#include <hip/hip_runtime.h>
#include <stdint.h>

#define N_PTS 4096
#define S_PTS 1024
#define K_SAMP 32

typedef __attribute__((ext_vector_type(8))) short bf16x8;
typedef __attribute__((ext_vector_type(4))) float f32x4;

#define GT1_S 104   // 96 cols + 8 pad (keeps b128 reads at <=2-way bank aliasing)
#define GT2_S 72    // 64 + 8
#define GT3_S 136   // 128 + 8

__device__ __forceinline__ short f2b(float f){
  unsigned u = __float_as_uint(f);
  u = u + 0x7fffu + ((u >> 16) & 1u);   // RNE to bf16
  return (short)(u >> 16);
}

// ---------------------------------------------------------------------------
// 1) FPS — one block per batch. Must match numpy f32 semantics bit-exactly:
//    no FMA contraction (use *_rn intrinsics), argmax ties -> lowest index.
// ---------------------------------------------------------------------------
__global__ __launch_bounds__(1024) void fps_kernel(const float* __restrict__ xyz,
                                                   float* __restrict__ out_newxyz,
                                                   float* __restrict__ out_inds){
  __shared__ float sx[N_PTS], sy[N_PTS], sz[N_PTS];
  __shared__ float rv[16];
  __shared__ int   ri[16];
  __shared__ int   swin;
  const int b = blockIdx.x;
  const int t = threadIdx.x;
  const float* xb = xyz + (size_t)b * N_PTS * 3;

  float px[4], py[4], pz[4], dist[4];
#pragma unroll
  for (int j = 0; j < 4; ++j){
    int p = j * 1024 + t;
    float x = xb[p*3+0], y = xb[p*3+1], z = xb[p*3+2];
    sx[p] = x; sy[p] = y; sz[p] = z;
    px[j] = x; py[j] = y; pz[j] = z;
    dist[j] = 1e10f;
  }
  __syncthreads();
  if (t == 0){
    out_inds[(size_t)b * S_PTS] = 0.0f;
    out_newxyz[(size_t)b*S_PTS*3 + 0] = sx[0];
    out_newxyz[(size_t)b*S_PTS*3 + 1] = sy[0];
    out_newxyz[(size_t)b*S_PTS*3 + 2] = sz[0];
  }
  int cur = 0;
  for (int it = 1; it < S_PTS; ++it){
    float lx = sx[cur], ly = sy[cur], lz = sz[cur];
    float bv = -1.0f; int bi = 0;
#pragma unroll
    for (int j = 0; j < 4; ++j){
      float dx = __fsub_rn(px[j], lx);
      float dy = __fsub_rn(py[j], ly);
      float dz = __fsub_rn(pz[j], lz);
      float d  = __fadd_rn(__fadd_rn(__fmul_rn(dx,dx), __fmul_rn(dy,dy)), __fmul_rn(dz,dz));
      float nd = fminf(dist[j], d);
      dist[j] = nd;
      if (nd > bv){ bv = nd; bi = j*1024 + t; }   // j ascending => index ascending
    }
    // wave64 butterfly argmax (ties -> lower index)
#pragma unroll
    for (int off = 1; off < 64; off <<= 1){
      float ov = __shfl_xor(bv, off);
      int   oi = __shfl_xor(bi, off);
      if (ov > bv || (ov == bv && oi < bi)){ bv = ov; bi = oi; }
    }
    if ((t & 63) == 0){ rv[t >> 6] = bv; ri[t >> 6] = bi; }
    __syncthreads();
    if (t < 64){
      float v = (t < 16) ? rv[t] : -1.0f;
      int   i = (t < 16) ? ri[t] : 0x7fffffff;
#pragma unroll
      for (int off = 1; off < 16; off <<= 1){
        float ov = __shfl_xor(v, off);
        int   oi = __shfl_xor(i, off);
        if (ov > v || (ov == v && oi < i)){ v = ov; i = oi; }
      }
      if (t == 0){
        swin = i;
        out_inds[(size_t)b*S_PTS + it] = (float)i;
        out_newxyz[((size_t)b*S_PTS + it)*3 + 0] = sx[i];
        out_newxyz[((size_t)b*S_PTS + it)*3 + 1] = sy[i];
        out_newxyz[((size_t)b*S_PTS + it)*3 + 2] = sz[i];
      }
    }
    __syncthreads();
    cur = swin;
  }
}

// ---------------------------------------------------------------------------
// 2) Weights -> bf16 in ws. W1 columns permuted: [feat(64), xyz(3), pad->96].
// ---------------------------------------------------------------------------
__global__ void wconv_kernel(const float* __restrict__ W1,
                             const float* __restrict__ W2,
                             const float* __restrict__ W3,
                             short* __restrict__ ws_w){
  short* w1 = ws_w;                       // 64 x 96
  short* w2 = ws_w + 64*96;               // 128 x 64
  short* w3 = ws_w + 64*96 + 128*64;      // 256 x 128
  int t = blockIdx.x * blockDim.x + threadIdx.x;
  int stride = gridDim.x * blockDim.x;
  for (int i = t; i < 64*96; i += stride){
    int m = i / 96, k = i - m*96;
    float v = 0.0f;
    if (k < 64)      v = W1[m*67 + 3 + k];
    else if (k < 67) v = W1[m*67 + (k - 64)];
    w1[i] = f2b(v);
  }
  for (int i = t; i < 128*64;  i += stride) w2[i] = f2b(W2[i]);
  for (int i = t; i < 256*128; i += stride) w3[i] = f2b(W3[i]);
}

// ---------------------------------------------------------------------------
// 3) Ball query — one wave per center, ordered first-32 selection via ballot.
// ---------------------------------------------------------------------------
__global__ __launch_bounds__(256) void ballquery_kernel(const float* __restrict__ xyz,
                                                        const float* __restrict__ newxyz,
                                                        int* __restrict__ idx_ws){
  const int lane = threadIdx.x & 63;
  const int c = blockIdx.x * 4 + (threadIdx.x >> 6);
  const int b = c >> 10;
  const float* xb = xyz + (size_t)b * N_PTS * 3;
  const float cx = newxyz[(size_t)c*3+0];
  const float cy = newxyz[(size_t)c*3+1];
  const float cz = newxyz[(size_t)c*3+2];
  const float R2 = 0.2f * 0.2f;
  int* idxp = idx_ws + (size_t)c * K_SAMP;
  int have = 0, first = -1;
  for (int chunk = 0; chunk < 64 && have < K_SAMP; ++chunk){
    int p = chunk * 64 + lane;
    float dx = __fsub_rn(xb[p*3+0], cx);
    float dy = __fsub_rn(xb[p*3+1], cy);
    float dz = __fsub_rn(xb[p*3+2], cz);
    float d2 = __fadd_rn(__fadd_rn(__fmul_rn(dx,dx), __fmul_rn(dy,dy)), __fmul_rn(dz,dz));
    bool hit = d2 < R2;
    unsigned long long mask = __ballot(hit);
    if (mask){
      if (first < 0) first = chunk*64 + (__ffsll(mask) - 1);
      int pre = __popcll(mask & ((1ull << lane) - 1ull));
      if (hit && (have + pre) < K_SAMP) idxp[have + pre] = p;
      have += __popcll(mask);
      if (have > K_SAMP) have = K_SAMP;
    }
  }
  if (first < 0) first = 0;
  if (lane < K_SAMP - have) idxp[have + lane] = first;
}

// ---------------------------------------------------------------------------
// 4) Fused group + 3-layer MLP + max-pool. One block (256 thr) per center.
//    gT layout: [point n][channel k] so B-fragments are contiguous b128 reads.
// ---------------------------------------------------------------------------
template<int M, int KC, int KPAD, int GS_IN, int GS_OUT>
__device__ __forceinline__ void layer_mfma(const short* __restrict__ Wl,
                                           const short* gin, short* gout,
                                           const float* __restrict__ sbias_l,
                                           int w, int quad, int col){
  for (int m0 = w*16; m0 < M; m0 += 64){
    f32x4 acc0 = {0,0,0,0}, acc1 = {0,0,0,0};
#pragma unroll
    for (int kc = 0; kc < KC; ++kc){
      bf16x8 a  = *reinterpret_cast<const bf16x8*>(Wl + (size_t)(m0+col)*KPAD + kc*32 + quad*8);
      bf16x8 b0 = *reinterpret_cast<const bf16x8*>(gin + col*GS_IN + kc*32 + quad*8);
      bf16x8 b1 = *reinterpret_cast<const bf16x8*>(gin + (16+col)*GS_IN + kc*32 + quad*8);
      acc0 = __builtin_amdgcn_mfma_f32_16x16x32_bf16(a, b0, acc0, 0, 0, 0);
      acc1 = __builtin_amdgcn_mfma_f32_16x16x32_bf16(a, b1, acc1, 0, 0, 0);
    }
    int rbase = m0 + quad*4;
    unsigned long long P0 = 0ull, P1 = 0ull;
#pragma unroll
    for (int r = 0; r < 4; ++r){
      float bias = sbias_l[rbase + r];
      unsigned long long q0 = (unsigned short)f2b(fmaxf(acc0[r] + bias, 0.0f));
      unsigned long long q1 = (unsigned short)f2b(fmaxf(acc1[r] + bias, 0.0f));
      P0 |= q0 << (16*r);
      P1 |= q1 << (16*r);
    }
    *reinterpret_cast<unsigned long long*>(&gout[col*GS_OUT + rbase])      = P0;
    *reinterpret_cast<unsigned long long*>(&gout[(16+col)*GS_OUT + rbase]) = P1;
  }
}

__global__ __launch_bounds__(256) void mlp_kernel(const float* __restrict__ xyz,
                                                  const float* __restrict__ feat,
                                                  const float* __restrict__ b1,
                                                  const float* __restrict__ b2,
                                                  const float* __restrict__ b3,
                                                  const float* __restrict__ newxyz,
                                                  const int* __restrict__ idx_ws,
                                                  const short* __restrict__ ws_w,
                                                  float* __restrict__ pooled){
  __shared__ __align__(16) short gT1[32*GT1_S];
  __shared__ __align__(16) short gT2[32*GT2_S];
  __shared__ __align__(16) short gT3[32*GT3_S];
  __shared__ int   sidx[32];
  __shared__ float sbias[448];
  const int t = threadIdx.x;
  const int c = blockIdx.x;
  const int b = c >> 10;
  const int lane = t & 63;
  const int w = t >> 6;
  const int quad = lane >> 4;
  const int col = lane & 15;

  const short* w1 = ws_w;
  const short* w2 = ws_w + 64*96;
  const short* w3 = ws_w + 64*96 + 128*64;

  if (t < 32) sidx[t] = idx_ws[(size_t)c*K_SAMP + t];
  for (int i = t; i < 448; i += 256)
    sbias[i] = (i < 64) ? b1[i] : (i < 192) ? b2[i-64] : b3[i-192];
  for (int i = t; i < 32*GT1_S; i += 256) gT1[i] = 0;
  __syncthreads();

  // gather: features -> gT1[p][0..63], relative xyz -> gT1[p][64..66]
  {
    int p = t >> 3, q = t & 7;
    int src = sidx[p];
    const float* fr = feat + ((size_t)b * N_PTS + src) * 64 + q*8;
    unsigned u[4];
#pragma unroll
    for (int jj = 0; jj < 4; ++jj){
      unsigned lo = (unsigned short)f2b(fr[2*jj]);
      unsigned hi = (unsigned short)f2b(fr[2*jj+1]);
      u[jj] = lo | (hi << 16);
    }
    uint4 v; v.x = u[0]; v.y = u[1]; v.z = u[2]; v.w = u[3];
    *reinterpret_cast<uint4*>(&gT1[p*GT1_S + q*8]) = v;
  }
  if (t < 32){
    int src = sidx[t];
    const float* pr = xyz + ((size_t)b * N_PTS + src) * 3;
    float cx = newxyz[(size_t)c*3+0];
    float cy = newxyz[(size_t)c*3+1];
    float cz = newxyz[(size_t)c*3+2];
    gT1[t*GT1_S + 64] = f2b(__fsub_rn(pr[0], cx));
    gT1[t*GT1_S + 65] = f2b(__fsub_rn(pr[1], cy));
    gT1[t*GT1_S + 66] = f2b(__fsub_rn(pr[2], cz));
  }
  __syncthreads();

  layer_mfma<64, 3, 96, GT1_S, GT2_S>(w1, gT1, gT2, sbias, w, quad, col);
  __syncthreads();
  layer_mfma<128, 2, 64, GT2_S, GT3_S>(w2, gT2, gT3, sbias + 64, w, quad, col);
  __syncthreads();

  // layer 3 + max-pool over the 32 points
  for (int m0 = w*16; m0 < 256; m0 += 64){
    f32x4 acc0 = {0,0,0,0}, acc1 = {0,0,0,0};
#pragma unroll
    for (int kc = 0; kc < 4; ++kc){
      bf16x8 a  = *reinterpret_cast<const bf16x8*>(w3 + (size_t)(m0+col)*128 + kc*32 + quad*8);
      bf16x8 b0 = *reinterpret_cast<const bf16x8*>(gT3 + col*GT3_S + kc*32 + quad*8);
      bf16x8 b1 = *reinterpret_cast<const bf16x8*>(gT3 + (16+col)*GT3_S + kc*32 + quad*8);
      acc0 = __builtin_amdgcn_mfma_f32_16x16x32_bf16(a, b0, acc0, 0, 0, 0);
      acc1 = __builtin_amdgcn_mfma_f32_16x16x32_bf16(a, b1, acc1, 0, 0, 0);
    }
    float vm[4];
#pragma unroll
    for (int r = 0; r < 4; ++r) vm[r] = fmaxf(acc0[r], acc1[r]);
#pragma unroll
    for (int off = 1; off < 16; off <<= 1){
#pragma unroll
      for (int r = 0; r < 4; ++r) vm[r] = fmaxf(vm[r], __shfl_xor(vm[r], off, 16));
    }
    if (col == 0){
#pragma unroll
      for (int r = 0; r < 4; ++r){
        int ch = m0 + quad*4 + r;
        pooled[(size_t)c*256 + ch] = fmaxf(vm[r] + sbias[192 + ch], 0.0f);
      }
    }
  }
}

// ---------------------------------------------------------------------------
// 5) transpose pooled (b,s,c) -> out (b,c,s), both sides coalesced
// ---------------------------------------------------------------------------
__global__ __launch_bounds__(256) void transpose_kernel(const float* __restrict__ pooled,
                                                        float* __restrict__ outf){
  __shared__ float tile[64][65];
  int b  = blockIdx.z;
  int s0 = blockIdx.x * 64;
  int c0 = blockIdx.y * 64;
#pragma unroll
  for (int k = 0; k < 16; ++k){
    int idx = threadIdx.x + k*256;
    int si = idx >> 6, ci = idx & 63;
    tile[si][ci] = pooled[((size_t)b*S_PTS + s0 + si)*256 + c0 + ci];
  }
  __syncthreads();
#pragma unroll
  for (int k = 0; k < 16; ++k){
    int idx = threadIdx.x + k*256;
    int ci = idx >> 6, si = idx & 63;
    outf[((size_t)b*256 + c0 + ci)*S_PTS + s0 + si] = tile[si][ci];
  }
}

extern "C" void kernel_launch(void* const* d_in, const int* in_sizes, int n_in,
                              void* d_out, int out_size, void* d_ws, size_t ws_size,
                              hipStream_t stream){
  const float* xyz  = (const float*)d_in[0];
  const float* feat = (const float*)d_in[1];
  const float* W1   = (const float*)d_in[2];
  const float* b1   = (const float*)d_in[3];
  const float* W2   = (const float*)d_in[4];
  const float* b2   = (const float*)d_in[5];
  const float* W3   = (const float*)d_in[6];
  const float* b3   = (const float*)d_in[7];

  float* out        = (float*)d_out;
  float* out_newxyz = out;                        // 8*1024*3   = 24576
  float* out_feat   = out + 24576;                // 8*256*1024 = 2097152
  float* out_inds   = out + 24576 + 2097152;      // 8*1024     = 8192 (as float)

  char*  ws     = (char*)d_ws;
  short* ws_w   = (short*)ws;                     // 94208 B of bf16 weights
  int*   idx_ws = (int*)(ws + 94208);             // 8*1024*32*4 = 1 MB
  float* pooled = (float*)(ws + 94208 + 1048576); // 8*1024*256*4 = 8 MB

  fps_kernel<<<8, 1024, 0, stream>>>(xyz, out_newxyz, out_inds);
  wconv_kernel<<<32, 256, 0, stream>>>(W1, W2, W3, ws_w);
  ballquery_kernel<<<2048, 256, 0, stream>>>(xyz, out_newxyz, idx_ws);
  mlp_kernel<<<8192, 256, 0, stream>>>(xyz, feat, b1, b2, b3, out_newxyz,
                                       idx_ws, ws_w, pooled);
  transpose_kernel<<<dim3(16, 4, 8), 256, 0, stream>>>(pooled, out_feat);
}

// Round 2
// 797.332 us; speedup vs baseline: 2.0176x; 2.0176x over previous
//
#include <hip/hip_runtime.h>
#include <stdint.h>

#define N_PTS 4096
#define S_PTS 1024
#define K_SAMP 32

typedef __attribute__((ext_vector_type(8))) short bf16x8;
typedef __attribute__((ext_vector_type(4))) float f32x4;

#define GT1_S 104   // 96 cols + 8 pad (keeps b128 reads at <=2-way bank aliasing)
#define GT2_S 72    // 64 + 8
#define GT3_S 136   // 128 + 8

__device__ __forceinline__ short f2b(float f){
  unsigned u = __float_as_uint(f);
  u = u + 0x7fffu + ((u >> 16) & 1u);   // RNE to bf16
  return (short)(u >> 16);
}

// DPP ctrl encodings (gfx9 lineage)
#define DPP_QUAD_XOR1 0xB1   // quad_perm(1,0,3,2)
#define DPP_QUAD_XOR2 0x4E   // quad_perm(2,3,0,1)
#define DPP_ROW_HMIRR 0x141  // row_half_mirror (xor-4 equivalent at quad granularity)
#define DPP_ROW_MIRR  0x140  // row_mirror (xor-8 equivalent)
#define DPP_ROW_BC15  0x142  // row_bcast15
#define DPP_ROW_BC31  0x143  // row_bcast31

// one butterfly/bcast stage of u64-key max (key = dist_bits<<32 | ~idx;
// max => largest dist, tie -> smallest idx). max is idempotent, so the
// bcast stages' partial-overlap duplicates are harmless.
template<int CTRL>
__device__ __forceinline__ unsigned long long kstep(unsigned long long k){
  unsigned lo = (unsigned)k, hi = (unsigned)(k >> 32);
  unsigned lo2 = (unsigned)__builtin_amdgcn_update_dpp((int)lo, (int)lo, CTRL, 0xF, 0xF, false);
  unsigned hi2 = (unsigned)__builtin_amdgcn_update_dpp((int)hi, (int)hi, CTRL, 0xF, 0xF, false);
  unsigned long long ok = ((unsigned long long)hi2 << 32) | lo2;
  return ok > k ? ok : k;
}

// ---------------------------------------------------------------------------
// 1) FPS — one block (4 waves) per batch, 16 pts/lane in registers.
//    Exact numpy f32 semantics: *_rn ops (no FMA), (x+y)+z sum order,
//    fminf, argmax tie -> lowest index (encoded in the u64 key).
//    Critical path per iter: 16x12 VALU + 6-stage DPP butterfly +
//    1 barrier + 1 slot ds_read_b64 + 2-stage quad reduce + 1 ds_read_b128.
// ---------------------------------------------------------------------------
__global__ __launch_bounds__(256) void fps_kernel(const float* __restrict__ xyz,
                                                  float* __restrict__ out_newxyz,
                                                  float* __restrict__ out_inds){
  __shared__ float4 c4[N_PTS];                       // 64 KB coord table
  __shared__ unsigned long long slots[2][4];         // double-buffered wave partials
  const int b = blockIdx.x;
  const int t = threadIdx.x;       // 0..255
  const int lane = t & 63;
  const int w = t >> 6;
  const float* xb = xyz + (size_t)b * N_PTS * 3;

  float px[16], py[16], pz[16], dist[16];
#pragma unroll
  for (int j = 0; j < 16; ++j){
    int p = j * 256 + t;
    float x = xb[p*3+0], y = xb[p*3+1], z = xb[p*3+2];
    px[j] = x; py[j] = y; pz[j] = z; dist[j] = 1e10f;
    c4[p] = make_float4(x, y, z, 0.0f);
  }
  __syncthreads();

  float lx, ly, lz;
  { float4 c0 = c4[0]; lx = c0.x; ly = c0.y; lz = c0.z; }
  if (t == 0){
    out_inds[(size_t)b * S_PTS] = 0.0f;
    out_newxyz[(size_t)b*S_PTS*3 + 0] = lx;
    out_newxyz[(size_t)b*S_PTS*3 + 1] = ly;
    out_newxyz[(size_t)b*S_PTS*3 + 2] = lz;
  }

  for (int it = 1; it < S_PTS; ++it){
    // --- local distance update + argmax (straight-line, registers only) ---
    float bv = -1.0f; int bj = 0;
#pragma unroll
    for (int j = 0; j < 16; ++j){
      float dx = __fsub_rn(px[j], lx);
      float dy = __fsub_rn(py[j], ly);
      float dz = __fsub_rn(pz[j], lz);
      float d  = __fadd_rn(__fadd_rn(__fmul_rn(dx,dx), __fmul_rn(dy,dy)), __fmul_rn(dz,dz));
      float nd = fminf(dist[j], d);
      dist[j] = nd;
      bool gt = nd > bv;               // strict >, j ascending => lowest j kept
      bv = gt ? nd : bv;
      bj = gt ? j  : bj;
    }
    int bi = bj * 256 + t;             // global point index
    unsigned long long k = ((unsigned long long)__float_as_uint(bv) << 32)
                         | (unsigned)(~bi);

    // --- wave64 argmax butterfly via DPP (all VALU-rate, no LDS) ---
    k = kstep<DPP_QUAD_XOR1>(k);
    k = kstep<DPP_QUAD_XOR2>(k);
    k = kstep<DPP_ROW_HMIRR>(k);
    k = kstep<DPP_ROW_MIRR >(k);
    k = kstep<DPP_ROW_BC15 >(k);
    k = kstep<DPP_ROW_BC31 >(k);       // lanes 48..63 now hold the wave total

    if (lane == 63) slots[it & 1][w] = k;
    __syncthreads();                   // the only barrier per iteration

    // --- cross-wave reduce: every lane reads one slot, quad butterfly ---
    unsigned long long sk = slots[it & 1][lane & 3];
    sk = kstep<DPP_QUAD_XOR1>(sk);
    sk = kstep<DPP_QUAD_XOR2>(sk);
    int cur = (int)(~(unsigned)sk);

    float4 cc = c4[cur];               // same-address broadcast, conflict-free
    lx = cc.x; ly = cc.y; lz = cc.z;
    if (t == 0){
      out_inds[(size_t)b*S_PTS + it] = (float)cur;
      out_newxyz[((size_t)b*S_PTS + it)*3 + 0] = lx;
      out_newxyz[((size_t)b*S_PTS + it)*3 + 1] = ly;
      out_newxyz[((size_t)b*S_PTS + it)*3 + 2] = lz;
    }
  }
}

// ---------------------------------------------------------------------------
// 2) Weights -> bf16 in ws. W1 columns permuted: [feat(64), xyz(3), pad->96].
// ---------------------------------------------------------------------------
__global__ void wconv_kernel(const float* __restrict__ W1,
                             const float* __restrict__ W2,
                             const float* __restrict__ W3,
                             short* __restrict__ ws_w){
  short* w1 = ws_w;                       // 64 x 96
  short* w2 = ws_w + 64*96;               // 128 x 64
  short* w3 = ws_w + 64*96 + 128*64;      // 256 x 128
  int t = blockIdx.x * blockDim.x + threadIdx.x;
  int stride = gridDim.x * blockDim.x;
  for (int i = t; i < 64*96; i += stride){
    int m = i / 96, k = i - m*96;
    float v = 0.0f;
    if (k < 64)      v = W1[m*67 + 3 + k];
    else if (k < 67) v = W1[m*67 + (k - 64)];
    w1[i] = f2b(v);
  }
  for (int i = t; i < 128*64;  i += stride) w2[i] = f2b(W2[i]);
  for (int i = t; i < 256*128; i += stride) w3[i] = f2b(W3[i]);
}

// ---------------------------------------------------------------------------
// 3) Ball query — one wave per center, ordered first-32 selection via ballot.
// ---------------------------------------------------------------------------
__global__ __launch_bounds__(256) void ballquery_kernel(const float* __restrict__ xyz,
                                                        const float* __restrict__ newxyz,
                                                        int* __restrict__ idx_ws){
  const int lane = threadIdx.x & 63;
  const int c = blockIdx.x * 4 + (threadIdx.x >> 6);
  const int b = c >> 10;
  const float* xb = xyz + (size_t)b * N_PTS * 3;
  const float cx = newxyz[(size_t)c*3+0];
  const float cy = newxyz[(size_t)c*3+1];
  const float cz = newxyz[(size_t)c*3+2];
  const float R2 = 0.2f * 0.2f;
  int* idxp = idx_ws + (size_t)c * K_SAMP;
  int have = 0, first = -1;
  for (int chunk = 0; chunk < 64 && have < K_SAMP; ++chunk){
    int p = chunk * 64 + lane;
    float dx = __fsub_rn(xb[p*3+0], cx);
    float dy = __fsub_rn(xb[p*3+1], cy);
    float dz = __fsub_rn(xb[p*3+2], cz);
    float d2 = __fadd_rn(__fadd_rn(__fmul_rn(dx,dx), __fmul_rn(dy,dy)), __fmul_rn(dz,dz));
    bool hit = d2 < R2;
    unsigned long long mask = __ballot(hit);
    if (mask){
      if (first < 0) first = chunk*64 + (__ffsll(mask) - 1);
      int pre = __popcll(mask & ((1ull << lane) - 1ull));
      if (hit && (have + pre) < K_SAMP) idxp[have + pre] = p;
      have += __popcll(mask);
      if (have > K_SAMP) have = K_SAMP;
    }
  }
  if (first < 0) first = 0;
  if (lane < K_SAMP - have) idxp[have + lane] = first;
}

// ---------------------------------------------------------------------------
// 4) Fused group + 3-layer MLP + max-pool. One block (256 thr) per center.
//    gT layout: [point n][channel k] so B-fragments are contiguous b128 reads.
// ---------------------------------------------------------------------------
template<int M, int KC, int KPAD, int GS_IN, int GS_OUT>
__device__ __forceinline__ void layer_mfma(const short* __restrict__ Wl,
                                           const short* gin, short* gout,
                                           const float* __restrict__ sbias_l,
                                           int w, int quad, int col){
  for (int m0 = w*16; m0 < M; m0 += 64){
    f32x4 acc0 = {0,0,0,0}, acc1 = {0,0,0,0};
#pragma unroll
    for (int kc = 0; kc < KC; ++kc){
      bf16x8 a  = *reinterpret_cast<const bf16x8*>(Wl + (size_t)(m0+col)*KPAD + kc*32 + quad*8);
      bf16x8 b0 = *reinterpret_cast<const bf16x8*>(gin + col*GS_IN + kc*32 + quad*8);
      bf16x8 b1 = *reinterpret_cast<const bf16x8*>(gin + (16+col)*GS_IN + kc*32 + quad*8);
      acc0 = __builtin_amdgcn_mfma_f32_16x16x32_bf16(a, b0, acc0, 0, 0, 0);
      acc1 = __builtin_amdgcn_mfma_f32_16x16x32_bf16(a, b1, acc1, 0, 0, 0);
    }
    int rbase = m0 + quad*4;
    unsigned long long P0 = 0ull, P1 = 0ull;
#pragma unroll
    for (int r = 0; r < 4; ++r){
      float bias = sbias_l[rbase + r];
      unsigned long long q0 = (unsigned short)f2b(fmaxf(acc0[r] + bias, 0.0f));
      unsigned long long q1 = (unsigned short)f2b(fmaxf(acc1[r] + bias, 0.0f));
      P0 |= q0 << (16*r);
      P1 |= q1 << (16*r);
    }
    *reinterpret_cast<unsigned long long*>(&gout[col*GS_OUT + rbase])      = P0;
    *reinterpret_cast<unsigned long long*>(&gout[(16+col)*GS_OUT + rbase]) = P1;
  }
}

__global__ __launch_bounds__(256) void mlp_kernel(const float* __restrict__ xyz,
                                                  const float* __restrict__ feat,
                                                  const float* __restrict__ b1,
                                                  const float* __restrict__ b2,
                                                  const float* __restrict__ b3,
                                                  const float* __restrict__ newxyz,
                                                  const int* __restrict__ idx_ws,
                                                  const short* __restrict__ ws_w,
                                                  float* __restrict__ pooled){
  __shared__ __align__(16) short gT1[32*GT1_S];
  __shared__ __align__(16) short gT2[32*GT2_S];
  __shared__ __align__(16) short gT3[32*GT3_S];
  __shared__ int   sidx[32];
  __shared__ float sbias[448];
  const int t = threadIdx.x;
  const int c = blockIdx.x;
  const int b = c >> 10;
  const int lane = t & 63;
  const int w = t >> 6;
  const int quad = lane >> 4;
  const int col = lane & 15;

  const short* w1 = ws_w;
  const short* w2 = ws_w + 64*96;
  const short* w3 = ws_w + 64*96 + 128*64;

  if (t < 32) sidx[t] = idx_ws[(size_t)c*K_SAMP + t];
  for (int i = t; i < 448; i += 256)
    sbias[i] = (i < 64) ? b1[i] : (i < 192) ? b2[i-64] : b3[i-192];
  for (int i = t; i < 32*GT1_S; i += 256) gT1[i] = 0;
  __syncthreads();

  // gather: features -> gT1[p][0..63], relative xyz -> gT1[p][64..66]
  {
    int p = t >> 3, q = t & 7;
    int src = sidx[p];
    const float* fr = feat + ((size_t)b * N_PTS + src) * 64 + q*8;
    unsigned u[4];
#pragma unroll
    for (int jj = 0; jj < 4; ++jj){
      unsigned lo = (unsigned short)f2b(fr[2*jj]);
      unsigned hi = (unsigned short)f2b(fr[2*jj+1]);
      u[jj] = lo | (hi << 16);
    }
    uint4 v; v.x = u[0]; v.y = u[1]; v.z = u[2]; v.w = u[3];
    *reinterpret_cast<uint4*>(&gT1[p*GT1_S + q*8]) = v;
  }
  if (t < 32){
    int src = sidx[t];
    const float* pr = xyz + ((size_t)b * N_PTS + src) * 3;
    float cx = newxyz[(size_t)c*3+0];
    float cy = newxyz[(size_t)c*3+1];
    float cz = newxyz[(size_t)c*3+2];
    gT1[t*GT1_S + 64] = f2b(__fsub_rn(pr[0], cx));
    gT1[t*GT1_S + 65] = f2b(__fsub_rn(pr[1], cy));
    gT1[t*GT1_S + 66] = f2b(__fsub_rn(pr[2], cz));
  }
  __syncthreads();

  layer_mfma<64, 3, 96, GT1_S, GT2_S>(w1, gT1, gT2, sbias, w, quad, col);
  __syncthreads();
  layer_mfma<128, 2, 64, GT2_S, GT3_S>(w2, gT2, gT3, sbias + 64, w, quad, col);
  __syncthreads();

  // layer 3 + max-pool over the 32 points
  for (int m0 = w*16; m0 < 256; m0 += 64){
    f32x4 acc0 = {0,0,0,0}, acc1 = {0,0,0,0};
#pragma unroll
    for (int kc = 0; kc < 4; ++kc){
      bf16x8 a  = *reinterpret_cast<const bf16x8*>(w3 + (size_t)(m0+col)*128 + kc*32 + quad*8);
      bf16x8 b0 = *reinterpret_cast<const bf16x8*>(gT3 + col*GT3_S + kc*32 + quad*8);
      bf16x8 b1 = *reinterpret_cast<const bf16x8*>(gT3 + (16+col)*GT3_S + kc*32 + quad*8);
      acc0 = __builtin_amdgcn_mfma_f32_16x16x32_bf16(a, b0, acc0, 0, 0, 0);
      acc1 = __builtin_amdgcn_mfma_f32_16x16x32_bf16(a, b1, acc1, 0, 0, 0);
    }
    float vm[4];
#pragma unroll
    for (int r = 0; r < 4; ++r) vm[r] = fmaxf(acc0[r], acc1[r]);
#pragma unroll
    for (int off = 1; off < 16; off <<= 1){
#pragma unroll
      for (int r = 0; r < 4; ++r) vm[r] = fmaxf(vm[r], __shfl_xor(vm[r], off, 16));
    }
    if (col == 0){
#pragma unroll
      for (int r = 0; r < 4; ++r){
        int ch = m0 + quad*4 + r;
        pooled[(size_t)c*256 + ch] = fmaxf(vm[r] + sbias[192 + ch], 0.0f);
      }
    }
  }
}

// ---------------------------------------------------------------------------
// 5) transpose pooled (b,s,c) -> out (b,c,s), both sides coalesced
// ---------------------------------------------------------------------------
__global__ __launch_bounds__(256) void transpose_kernel(const float* __restrict__ pooled,
                                                        float* __restrict__ outf){
  __shared__ float tile[64][65];
  int b  = blockIdx.z;
  int s0 = blockIdx.x * 64;
  int c0 = blockIdx.y * 64;
#pragma unroll
  for (int k = 0; k < 16; ++k){
    int idx = threadIdx.x + k*256;
    int si = idx >> 6, ci = idx & 63;
    tile[si][ci] = pooled[((size_t)b*S_PTS + s0 + si)*256 + c0 + ci];
  }
  __syncthreads();
#pragma unroll
  for (int k = 0; k < 16; ++k){
    int idx = threadIdx.x + k*256;
    int ci = idx >> 6, si = idx & 63;
    outf[((size_t)b*256 + c0 + ci)*S_PTS + s0 + si] = tile[si][ci];
  }
}

extern "C" void kernel_launch(void* const* d_in, const int* in_sizes, int n_in,
                              void* d_out, int out_size, void* d_ws, size_t ws_size,
                              hipStream_t stream){
  const float* xyz  = (const float*)d_in[0];
  const float* feat = (const float*)d_in[1];
  const float* W1   = (const float*)d_in[2];
  const float* b1   = (const float*)d_in[3];
  const float* W2   = (const float*)d_in[4];
  const float* b2   = (const float*)d_in[5];
  const float* W3   = (const float*)d_in[6];
  const float* b3   = (const float*)d_in[7];

  float* out        = (float*)d_out;
  float* out_newxyz = out;                        // 8*1024*3   = 24576
  float* out_feat   = out + 24576;                // 8*256*1024 = 2097152
  float* out_inds   = out + 24576 + 2097152;      // 8*1024     = 8192 (as float)

  char*  ws     = (char*)d_ws;
  short* ws_w   = (short*)ws;                     // 94208 B of bf16 weights
  int*   idx_ws = (int*)(ws + 94208);             // 8*1024*32*4 = 1 MB
  float* pooled = (float*)(ws + 94208 + 1048576); // 8*1024*256*4 = 8 MB

  wconv_kernel<<<32, 256, 0, stream>>>(W1, W2, W3, ws_w);
  fps_kernel<<<8, 256, 0, stream>>>(xyz, out_newxyz, out_inds);
  ballquery_kernel<<<2048, 256, 0, stream>>>(xyz, out_newxyz, idx_ws);
  mlp_kernel<<<8192, 256, 0, stream>>>(xyz, feat, b1, b2, b3, out_newxyz,
                                       idx_ws, ws_w, pooled);
  transpose_kernel<<<dim3(16, 4, 8), 256, 0, stream>>>(pooled, out_feat);
}